// Round 7
// baseline (459.653 us; speedup 1.0000x reference)
//
#include <hip/hip_runtime.h>
#include <math.h>

// Problem constants (from reference setup_inputs).
constexpr int B_ = 2048;
constexpr int C_ = 9605;
constexpr int L_ = 8;
constexpr int TOPK_ = 16;
constexpr int CAPQ_ = 512;       // small path: candidate float4 slots
constexpr int CAPC_ = 512;       // big path: candidate float slots per row (~219 expected)
constexpr float T0_ = 2.0f;      // candidate prefilter (16th largest ~2.95); guarded exact
constexpr int CPAD_ = 9728;      // small path: padded code bytes
constexpr int CS_ = 9632;        // big path: bytes per lead-shifted code copy (2408 dwords)

__device__ __forceinline__ float sigm(float v) { return 1.0f / (1.0f + expf(-v)); }

// our_rank_loss: d = x2 - x1 + margin; s = sigmoid(5d); 2s when violated (d>0)
__device__ __forceinline__ float rank_loss(float x1, float x2) {
  float d = x2 - x1 + 0.05f;
  float s = 1.0f / (1.0f + expf(-5.0f * d));
  return (d > 0.0f) ? 2.0f * s : s;
}

// Order-preserving float->uint key (ascending) and inverse (all floats).
__device__ __forceinline__ unsigned int fkey(float v) {
  unsigned int u = __float_as_uint(v);
  return u ^ ((u & 0x80000000u) ? 0xFFFFFFFFu : 0x80000000u);
}
__device__ __forceinline__ float fkeyinv(unsigned int k) {
  unsigned int u = (k & 0x80000000u) ? (k ^ 0x80000000u) : ~k;
  return __uint_as_float(u);
}

// ===================== BIG PATH (barrier-free dense sweep) =================

// Setup: FOUR lead-shifted packed code copies + init per-row tables.
__global__ void setup_kernel(const int* __restrict__ mask,
                             unsigned char* __restrict__ code4,
                             unsigned int* __restrict__ gslotG,
                             unsigned int* __restrict__ gtG,
                             unsigned int* __restrict__ gtnG,
                             int* __restrict__ cntG) {
  const int tid = blockIdx.x * 256 + threadIdx.x;  // grid 38*256 = 9728 threads
  if (tid < CS_ + 3) {
    unsigned char cd = 0xFF;
    if (tid < C_) {
#pragma unroll
      for (int l = L_ - 1; l >= 0; --l)
        if (mask[l * C_ + tid] != 0) cd = (unsigned char)l;
    }
#pragma unroll
    for (int ld = 0; ld < 4; ++ld) {
      int p = tid - ld;
      if (p >= 0 && p < CS_) code4[ld * CS_ + p] = cd;
    }
  }
  for (int i = tid; i < B_ * 8; i += 9728) gslotG[i] = 0x80000000u;  // key(+0.0)
  for (int i = tid; i < B_; i += 9728) { gtG[i] = 0u; gtnG[i] = 0u; cntG[i] = 0; }
}

// Barrier-free fused sweep. Dense grid-stride quads; NO __syncthreads in the
// loop (the r0-r6 kernels drained vmcnt(0) at every barrier -> no memory
// overlap). Group maxima accumulate in WAVE-PRIVATE LDS slots via ds_max
// (fire-and-forget), flushed per step by 16 lanes to the L2-resident global
// table. Candidates / label bits: rare direct global atomics.
__global__ void __launch_bounds__(256, 8) fused_sweep(
    const float* __restrict__ x, const float* __restrict__ y,
    const float* __restrict__ yn, const unsigned char* __restrict__ code4,
    unsigned int* __restrict__ gslotG, unsigned int* __restrict__ gtG,
    unsigned int* __restrict__ gtnG, int* __restrict__ cntG,
    float* __restrict__ candG) {
  constexpr int NE = B_ * C_;        // 19,671,040 (divisible by 4)
  constexpr int NQ = NE / 4;         // 4,917,760 quads
  constexpr int TT = 2048 * 256;     // grid threads
  __shared__ unsigned int wslot[4][16];  // [wave][rr*8+cd]; 0 == empty

  const int t = threadIdx.x;
  const int w = t >> 6;
  const int ln = t & 63;
  const int gtid = (int)blockIdx.x * 256 + t;

#pragma unroll 1
  for (int step = 0; step < 10; ++step) {
    const int q = gtid + step * TT;
    // Wave-uniform first row of this wave's 256-element span (<=2 rows).
    const int efirst = ((int)blockIdx.x * 256 + (w << 6) + step * TT) << 2;
    const int rowbase = efirst / C_;

    if (ln < 16) wslot[w][ln] = 0u;   // wave-private: no barrier needed
    __threadfence_block();            // order init before this wave's ds_max

    if (q < NQ) {
      const int e0 = q << 2;
      float4 X = *reinterpret_cast<const float4*>(x + e0);
      float4 Y = *reinterpret_cast<const float4*>(y + e0);
      float4 N = *reinterpret_cast<const float4*>(yn + e0);
      int r0 = e0 / C_;
      int cc = e0 - r0 * C_;
      int rr = r0 - rowbase;          // 0 or 1

      auto pe = [&](float xv, float yv, float nv, unsigned int cd, int rrk) {
        const int row = rowbase + rrk;
        if (cd < 8u) {
          if (xv > 0.0f)
            atomicMax(&wslot[w][(rrk << 3) + (int)cd],
                      __float_as_uint(xv) | 0x80000000u);
          if (yv > 0.0f) atomicOr(&gtG[row], 1u << cd);    // ~6K total: rare
          if (nv > 0.0f) atomicOr(&gtnG[row], 1u << cd);
        }
        if (xv > T0_) {                                    // ~2.3% of elems
          int p = atomicAdd(&cntG[row], 1);
          if (p < CAPC_) candG[(size_t)row * CAPC_ + p] = xv;
        }
      };

      if (cc + 3 < C_) {  // fast: quad within one row, one code dword
        unsigned int cw = *reinterpret_cast<const unsigned int*>(
            code4 + (size_t)((cc & 3) * CS_ + (cc & ~3)));
        pe(X.x, Y.x, N.x, cw & 0xFFu, rr);
        pe(X.y, Y.y, N.y, (cw >> 8) & 0xFFu, rr);
        pe(X.z, Y.z, N.z, (cw >> 16) & 0xFFu, rr);
        pe(X.w, Y.w, N.w, cw >> 24, rr);
      } else {            // row-wrap quad (~2048 total): per-element
        const float xv[4] = {X.x, X.y, X.z, X.w};
        const float yv[4] = {Y.x, Y.y, Y.z, Y.w};
        const float nv[4] = {N.x, N.y, N.z, N.w};
        int ccc = cc, rrr = rr;
#pragma unroll
        for (int k = 0; k < 4; ++k) {
          pe(xv[k], yv[k], nv[k], (unsigned int)code4[ccc], rrr);
          if (++ccc == C_) { ccc = 0; ++rrr; }
        }
      }
    }

    __threadfence_block();  // drain this wave's ds ops before cross-lane read
    if (ln < 16) {
      unsigned int v = wslot[w][ln];
      int row = rowbase + (ln >> 3);
      if (v != 0u && row < B_) atomicMax(&gslotG[row * 8 + (ln & 7)], v);
    }
  }
}

// Finish: one wave per row. Exact 16th-largest from candidates (cnt>=16 =>
// 16th-largest > T0 => fully captured); else exact bisection over the row.
__global__ void finish_kernel(
    const float* __restrict__ x, const unsigned int* __restrict__ gslotG,
    const unsigned int* __restrict__ gtG, const unsigned int* __restrict__ gtnG,
    const int* __restrict__ cntG, const float* __restrict__ candG,
    float* __restrict__ loss) {
  const int r = blockIdx.x;
  const int t = threadIdx.x;  // 64 = one wave; no barriers needed
  const int cnt = cntG[r];
  float x16;
  if (cnt >= TOPK_ && cnt <= CAPC_) {
    const float* cf = candG + (size_t)r * CAPC_;
    unsigned int ku[CAPC_ / 64];
#pragma unroll
    for (int k = 0; k < CAPC_ / 64; ++k) {
      int i = t + (k << 6);
      ku[k] = (i < cnt) ? fkey(cf[i]) : 0u;
    }
    unsigned int lo = 0u, hi = 0xFFFFFFFFu;
#pragma unroll 1
    for (int it = 0; it < 32 && lo < hi; ++it) {
      unsigned int mid = lo + ((hi - lo) >> 1) + 1u;
      int c16 = 0;
#pragma unroll
      for (int k = 0; k < CAPC_ / 64; ++k) c16 += (ku[k] >= mid) ? 1 : 0;
#pragma unroll
      for (int off = 32; off > 0; off >>= 1) c16 += __shfl_xor(c16, off, 64);
      if (c16 >= TOPK_) lo = mid; else hi = mid - 1u;
    }
    x16 = fkeyinv(lo);
  } else {
    const float* xr = x + (size_t)r * C_;
    unsigned int lo = 0u, hi = 0xFFFFFFFFu;
#pragma unroll 1
    for (int it = 0; it < 32 && lo < hi; ++it) {
      unsigned int mid = lo + ((hi - lo) >> 1) + 1u;
      int cl = 0;
      for (int c = t; c < C_; c += 64) cl += (fkey(xr[c]) >= mid) ? 1 : 0;
#pragma unroll
      for (int off = 32; off > 0; off >>= 1) cl += __shfl_xor(cl, off, 64);
      if (cl >= TOPK_) lo = mid; else hi = mid - 1u;
    }
    x16 = fkeyinv(lo);
  }
  if (t == 0) {
    float thres = fmaxf(sigm(x16), 0.3f);
    unsigned int gtb = gtG[r], gnb = gtnG[r];
    float caseB = 0.0f, unio = -INFINITY, negmax = -INFINITY;
#pragma unroll
    for (int l = 0; l < L_; ++l) {
      float gm = __uint_as_float(gslotG[r * 8 + l] ^ 0x80000000u);
      float g = sigm(gm);
      unio = fmaxf(unio, g);
      caseB += ((gtb >> l) & 1u) ? rank_loss(g, thres) : rank_loss(thres, g);
      if ((gnb >> l) & 1u) negmax = fmaxf(negmax, g);
    }
    float negscore = (gnb != 0u) ? negmax : 0.0f;
    float caseA = 0.5f * rank_loss(thres, unio) + 0.5f * rank_loss(thres, negscore);
    loss[r] = (gtb != 0u) ? caseB : caseA;
  }
}

// CONTROL: pure streaming read of the same 236 MB (m13-copy-shaped).
// Its profiled dur/FETCH = the platform ceiling for this data in this
// harness. Runs after finish_kernel; sink overwrites consumed candG.
__global__ void __launch_bounds__(256) bw_probe(
    const float* __restrict__ x, const float* __restrict__ y,
    const float* __restrict__ yn, float* __restrict__ sink) {
  constexpr int NQ = B_ * C_ / 4;
  constexpr int TT = 2048 * 256;
  const int gtid = (int)blockIdx.x * 256 + threadIdx.x;
  float s = 0.0f;
  for (int q = gtid; q < NQ; q += TT) {
    float4 a = *reinterpret_cast<const float4*>(x + (q << 2));
    float4 b = *reinterpret_cast<const float4*>(y + (q << 2));
    float4 c = *reinterpret_cast<const float4*>(yn + (q << 2));
    s += a.x + a.y + a.z + a.w + b.x + b.y + b.z + b.w + c.x + c.y + c.z + c.w;
  }
  if (s == 1234.56789f) sink[0] = s;  // keep loads live; store ~never fires
}

// ===================== SMALL PATH (round-3 proven kernels) =================

__global__ void build_code_kernel(const int* __restrict__ mask,
                                  unsigned char* __restrict__ code) {
  int c = blockIdx.x * 256 + threadIdx.x;
  if (c >= CPAD_) return;
  unsigned char cd = 0xFF;
  if (c < C_) {
#pragma unroll
    for (int l = L_ - 1; l >= 0; --l)
      if (mask[l * C_ + c] != 0) cd = (unsigned char)l;
  }
  code[c] = cd;
}

__global__ void __launch_bounds__(512, 4) row_loss_kernel(
    const float* __restrict__ x, const float* __restrict__ y,
    const float* __restrict__ yn, const unsigned char* __restrict__ code,
    float* __restrict__ loss) {
  __shared__ unsigned int lds_code[2404];
  __shared__ float4 cand4[CAPQ_];
  __shared__ unsigned int gslot[L_];
  __shared__ int cand_cnt;
  __shared__ unsigned int gt_bits, gtn_bits;
  __shared__ float s_x16;
  __shared__ int s_flag, s_red;

  const int t = threadIdx.x;
  const int b = blockIdx.x;
  const int lead = (4 - ((b * C_) & 3)) & 3;
  const int n4 = (C_ - lead) >> 2;

  const float* xb = x + (size_t)(b * C_ + lead);
  const float* yb = y + (size_t)(b * C_ + lead);
  const float* nb = yn + (size_t)(b * C_ + lead);

  if (t < L_) gslot[t] = 0x80000000u;
  if (t == 0) { cand_cnt = 0; gt_bits = 0u; gtn_bits = 0u; s_flag = 0; }

  const unsigned int* cdw = (const unsigned int*)code;
  if (lead == 0) {
    for (int j = t; j < n4; j += 512) lds_code[j] = cdw[j];
  } else {
    const int sh = lead << 3;
    for (int j = t; j < n4; j += 512) {
      unsigned int d0 = cdw[j], d1 = cdw[j + 1];
      lds_code[j] = (d0 >> sh) | (d1 << (32 - sh));
    }
  }
  __syncthreads();

  float4 XA, YA, NA, XB, YB, NB;

  auto ISSUE = [&](int j, float4& X, float4& Y, float4& N) {
    int js = (j < n4) ? j : 0;
    unsigned int vo = (unsigned int)js << 4;
    asm volatile("global_load_dwordx4 %0, %1, %2" : "=v"(X) : "v"(vo), "s"(xb));
    asm volatile("global_load_dwordx4 %0, %1, %2" : "=v"(Y) : "v"(vo), "s"(yb));
    asm volatile("global_load_dwordx4 %0, %1, %2" : "=v"(N) : "v"(vo), "s"(nb));
  };

  auto PROC = [&](const float4& X, const float4& Y, const float4& N, int j) {
    if (j >= n4) return;
    unsigned int cw = lds_code[j];
    float mx = fmaxf(fmaxf(X.x, X.y), fmaxf(X.z, X.w));
    if (mx > T0_) {
      int p = atomicAdd(&cand_cnt, 1);
      if (p < CAPQ_) cand4[p] = X;
    }
    {
      unsigned int cd, k;
      cd = cw & 0xFFu;
      if (cd < 8u && X.x > 0.0f) { k = __float_as_uint(X.x) | 0x80000000u; if (k > gslot[cd]) atomicMax(&gslot[cd], k); }
      cd = (cw >> 8) & 0xFFu;
      if (cd < 8u && X.y > 0.0f) { k = __float_as_uint(X.y) | 0x80000000u; if (k > gslot[cd]) atomicMax(&gslot[cd], k); }
      cd = (cw >> 16) & 0xFFu;
      if (cd < 8u && X.z > 0.0f) { k = __float_as_uint(X.z) | 0x80000000u; if (k > gslot[cd]) atomicMax(&gslot[cd], k); }
      cd = cw >> 24;
      if (cd < 8u && X.w > 0.0f) { k = __float_as_uint(X.w) | 0x80000000u; if (k > gslot[cd]) atomicMax(&gslot[cd], k); }
    }
    float sy = Y.x + Y.y + Y.z + Y.w + N.x + N.y + N.z + N.w;
    if (sy > 0.0f) {
      unsigned int d;
      d = cw & 0xFFu;
      if (d < 8u) { if (Y.x > 0.0f && !((gt_bits >> d) & 1u)) atomicOr(&gt_bits, 1u << d); if (N.x > 0.0f && !((gtn_bits >> d) & 1u)) atomicOr(&gtn_bits, 1u << d); }
      d = (cw >> 8) & 0xFFu;
      if (d < 8u) { if (Y.y > 0.0f && !((gt_bits >> d) & 1u)) atomicOr(&gt_bits, 1u << d); if (N.y > 0.0f && !((gtn_bits >> d) & 1u)) atomicOr(&gtn_bits, 1u << d); }
      d = (cw >> 16) & 0xFFu;
      if (d < 8u) { if (Y.z > 0.0f && !((gt_bits >> d) & 1u)) atomicOr(&gt_bits, 1u << d); if (N.z > 0.0f && !((gtn_bits >> d) & 1u)) atomicOr(&gtn_bits, 1u << d); }
      d = cw >> 24;
      if (d < 8u) { if (Y.w > 0.0f && !((gt_bits >> d) & 1u)) atomicOr(&gt_bits, 1u << d); if (N.w > 0.0f && !((gtn_bits >> d) & 1u)) atomicOr(&gtn_bits, 1u << d); }
    }
  };

  ISSUE(t, XA, YA, NA);
  ISSUE(t + 512, XB, YB, NB);

  asm volatile("s_waitcnt vmcnt(3)" ::: "memory");
  __builtin_amdgcn_sched_barrier(0);
  PROC(XA, YA, NA, t);
  ISSUE(t + 1024, XA, YA, NA);

  asm volatile("s_waitcnt vmcnt(3)" ::: "memory");
  __builtin_amdgcn_sched_barrier(0);
  PROC(XB, YB, NB, t + 512);
  ISSUE(t + 1536, XB, YB, NB);

  asm volatile("s_waitcnt vmcnt(3)" ::: "memory");
  __builtin_amdgcn_sched_barrier(0);
  PROC(XA, YA, NA, t + 1024);
  ISSUE(t + 2048, XA, YA, NA);

  asm volatile("s_waitcnt vmcnt(3)" ::: "memory");
  __builtin_amdgcn_sched_barrier(0);
  PROC(XB, YB, NB, t + 1536);

  asm volatile("s_waitcnt vmcnt(0)" ::: "memory");
  __builtin_amdgcn_sched_barrier(0);
  PROC(XA, YA, NA, t + 2048);

  if (t < 4) {
    auto sc = [&](int c) {
      float xv = x[(size_t)b * C_ + c], yv = y[(size_t)b * C_ + c],
            nv = yn[(size_t)b * C_ + c];
      unsigned int cd = code[c];
      if (cd < 8u) {
        if (xv > 0.0f) atomicMax(&gslot[cd], __float_as_uint(xv) | 0x80000000u);
        if (yv > 0.0f) atomicOr(&gt_bits, 1u << cd);
        if (nv > 0.0f) atomicOr(&gtn_bits, 1u << cd);
      }
      if (xv > T0_) {
        int p = atomicAdd(&cand_cnt, 1);
        if (p < CAPQ_) cand4[p] = make_float4(xv, -INFINITY, -INFINITY, -INFINITY);
      }
    };
    if (t < lead) sc(t);
    int c2 = lead + (n4 << 2) + t;
    if (c2 < C_) sc(c2);
  }
  __syncthreads();

  const int qn = cand_cnt;
  const bool ok_path = (qn >= 4) && (qn <= CAPQ_);
  if (ok_path && t < 64) {
    const float* cf = reinterpret_cast<const float*>(cand4);
    const int nvv = qn << 2;
    unsigned int ku[32];
#pragma unroll
    for (int k = 0; k < 32; ++k) {
      int i = t + (k << 6);
      ku[k] = (i < nvv) ? fkey(cf[i]) : 0u;
    }
    unsigned int lo = 0u, hi = 0xFFFFFFFFu;
#pragma unroll 1
    for (int it = 0; it < 32 && lo < hi; ++it) {
      unsigned int mid = lo + ((hi - lo) >> 1) + 1u;
      int c16 = 0;
#pragma unroll
      for (int k = 0; k < 32; ++k) c16 += (ku[k] >= mid) ? 1 : 0;
#pragma unroll
      for (int off = 32; off > 0; off >>= 1) c16 += __shfl_xor(c16, off, 64);
      if (c16 >= TOPK_) lo = mid; else hi = mid - 1u;
    }
    if (t == 0) {
      float v = fkeyinv(lo);
      s_x16 = v;
      s_flag = (v > T0_) ? 1 : 0;
    }
  }
  __syncthreads();
  if (!(ok_path && s_flag != 0)) {
    const float* xr = x + (size_t)b * C_;
    unsigned int lo = 0u, hi = 0xFFFFFFFFu;
    for (int it = 0; it < 32; ++it) {
      if (lo >= hi) break;
      unsigned int mid = lo + ((hi - lo) >> 1) + 1u;
      if (t == 0) s_red = 0;
      __syncthreads();
      int cl = 0;
      for (int c = t; c < C_; c += 512) cl += (fkey(xr[c]) >= mid) ? 1 : 0;
      atomicAdd(&s_red, cl);
      __syncthreads();
      int total = s_red;
      __syncthreads();
      if (total >= TOPK_) lo = mid; else hi = mid - 1u;
    }
    if (t == 0) s_x16 = fkeyinv(lo);
  }
  __syncthreads();

  if (t == 0) {
    float thres = fmaxf(sigm(s_x16), 0.3f);
    unsigned int gtb = gt_bits, gnb = gtn_bits;
    float caseB = 0.0f, unio = -INFINITY, negmax = -INFINITY;
#pragma unroll
    for (int l = 0; l < L_; ++l) {
      float gm = __uint_as_float(gslot[l] ^ 0x80000000u);
      float g = sigm(gm);
      unio = fmaxf(unio, g);
      caseB += ((gtb >> l) & 1u) ? rank_loss(g, thres) : rank_loss(thres, g);
      if ((gnb >> l) & 1u) negmax = fmaxf(negmax, g);
    }
    float negscore = (gnb != 0u) ? negmax : 0.0f;
    float caseA = 0.5f * rank_loss(thres, unio) + 0.5f * rank_loss(thres, negscore);
    loss[b] = (gtb != 0u) ? caseB : caseA;
  }
}

// Deterministic mean of the 2048 per-row losses (shared by both paths).
__global__ void mean_kernel(const float* __restrict__ loss, float* __restrict__ out) {
  const int t = threadIdx.x;
  float s = 0.0f;
  for (int i = t; i < B_; i += 256) s += loss[i];
#pragma unroll
  for (int off = 32; off > 0; off >>= 1) s += __shfl_xor(s, off, 64);
  __shared__ float part[4];
  if ((t & 63) == 0) part[t >> 6] = s;
  __syncthreads();
  if (t == 0) out[0] = (part[0] + part[1] + part[2] + part[3]) * (1.0f / (float)B_);
}

extern "C" void kernel_launch(void* const* d_in, const int* in_sizes, int n_in,
                              void* d_out, int out_size, void* d_ws, size_t ws_size,
                              hipStream_t stream) {
  const float* x = (const float*)d_in[0];
  const float* y = (const float*)d_in[1];
  const float* yn = (const float*)d_in[2];
  const int* mask = (const int*)d_in[3];  // bool promoted to int32 by harness

  // Big-path workspace layout (proven taken in rounds 4/6).
  constexpr size_t OFF_LOSS = 0;                              // 2048 f32
  constexpr size_t OFF_CODE4 = 8192;                          // 4*CS_ bytes
  constexpr size_t OFF_GSLOT = OFF_CODE4 + 4 * CS_;           // 2048*8 u32
  constexpr size_t OFF_GT = OFF_GSLOT + B_ * 8 * 4;           // 2048 u32
  constexpr size_t OFF_GTN = OFF_GT + B_ * 4;                 // 2048 u32
  constexpr size_t OFF_CNT = OFF_GTN + B_ * 4;                // 2048 i32
  constexpr size_t OFF_CAND = OFF_CNT + B_ * 4;               // 2048*CAPC_ f32
  constexpr size_t WS_BIG = OFF_CAND + (size_t)B_ * CAPC_ * 4;  // ~4.33 MB

  float* loss = (float*)((char*)d_ws + OFF_LOSS);

  if (ws_size >= WS_BIG) {
    unsigned char* code4 = (unsigned char*)d_ws + OFF_CODE4;
    unsigned int* gslotG = (unsigned int*)((char*)d_ws + OFF_GSLOT);
    unsigned int* gtG = (unsigned int*)((char*)d_ws + OFF_GT);
    unsigned int* gtnG = (unsigned int*)((char*)d_ws + OFF_GTN);
    int* cntG = (int*)((char*)d_ws + OFF_CNT);
    float* candG = (float*)((char*)d_ws + OFF_CAND);

    hipLaunchKernelGGL(setup_kernel, dim3(38), dim3(256), 0, stream,
                       mask, code4, gslotG, gtG, gtnG, cntG);
    hipLaunchKernelGGL(fused_sweep, dim3(2048), dim3(256), 0, stream,
                       x, y, yn, code4, gslotG, gtG, gtnG, cntG, candG);
    hipLaunchKernelGGL(finish_kernel, dim3(2048), dim3(64), 0, stream,
                       x, gslotG, gtG, gtnG, cntG, candG, loss);
    hipLaunchKernelGGL(bw_probe, dim3(2048), dim3(256), 0, stream,
                       x, y, yn, candG);  // candG consumed; safe sink
  } else {
    unsigned char* code = (unsigned char*)d_ws + B_ * sizeof(float);
    hipLaunchKernelGGL(build_code_kernel, dim3((CPAD_ + 255) / 256), dim3(256), 0,
                       stream, mask, code);
    hipLaunchKernelGGL(row_loss_kernel, dim3(B_), dim3(512), 0, stream,
                       x, y, yn, code, loss);
  }
  hipLaunchKernelGGL(mean_kernel, dim3(1), dim3(256), 0, stream,
                     loss, (float*)d_out);
}

// Round 8
// 254.800 us; speedup vs baseline: 1.8040x; 1.8040x over previous
//
#include <hip/hip_runtime.h>
#include <math.h>

// Problem constants (from reference setup_inputs).
constexpr int B_ = 2048;
constexpr int C_ = 9605;
constexpr int L_ = 8;
constexpr int TOPK_ = 16;
constexpr int CAPQ_ = 384;     // candidate float4 (quad) slots (~210 expected, +12σ)
constexpr float T0_ = 2.0f;    // candidate prefilter (16th largest ~2.95); guarded exact
constexpr int CS_ = 9632;      // bytes per lead-shifted code copy (2408 dwords)

__device__ __forceinline__ float sigm(float v) { return 1.0f / (1.0f + expf(-v)); }

// our_rank_loss: d = x2 - x1 + margin; s = sigmoid(5d); 2s when violated (d>0)
__device__ __forceinline__ float rank_loss(float x1, float x2) {
  float d = x2 - x1 + 0.05f;
  float s = 1.0f / (1.0f + expf(-5.0f * d));
  return (d > 0.0f) ? 2.0f * s : s;
}

// Order-preserving float->uint key (ascending) and inverse (all floats).
__device__ __forceinline__ unsigned int fkey(float v) {
  unsigned int u = __float_as_uint(v);
  return u ^ ((u & 0x80000000u) ? 0xFFFFFFFFu : 0x80000000u);
}
__device__ __forceinline__ float fkeyinv(unsigned int k) {
  unsigned int u = (k & 0x80000000u) ? (k ^ 0x80000000u) : ~k;
  return __uint_as_float(u);
}

// Setup: FOUR lead-shifted packed code copies (copy ld, byte p = group code of
// class p+ld; 0xFF pad) + zero the label-bit tables.
__global__ void setup_kernel(const int* __restrict__ mask,
                             unsigned char* __restrict__ code4,
                             unsigned int* __restrict__ gtG,
                             unsigned int* __restrict__ gtnG) {
  const int tid = blockIdx.x * 256 + threadIdx.x;  // grid 38*256 = 9728 threads
  if (tid < CS_ + 3) {
    unsigned char cd = 0xFF;
    if (tid < C_) {
#pragma unroll
      for (int l = L_ - 1; l >= 0; --l)
        if (mask[l * C_ + tid] != 0) cd = (unsigned char)l;
    }
#pragma unroll
    for (int ld = 0; ld < 4; ++ld) {
      int p = tid - ld;
      if (p >= 0 && p < CS_) code4[ld * CS_ + p] = cd;
    }
  }
  if (tid < B_) { gtG[tid] = 0u; gtnG[tid] = 0u; }
}

// Sweep: 3*2048 blocks; group g = bid>>11 owns ONE stream (0=x, 1=y, 2=yn) of
// row r = bid&2047 (row-exclusive: no global atomics anywhere).
// x-path design (the round-8 variable): branchless inner loop, per-THREAD
// private LDS slots updated with fire-and-forget ds_max (distinct address per
// lane -> zero serialization, zero read-dependency, zero exec-mask regions),
// ZERO in-loop barriers, one final tree-reduce + in-block exact top-16.
__global__ void __launch_bounds__(256, 8) rows3_kernel(
    const float* __restrict__ x, const float* __restrict__ y,
    const float* __restrict__ yn, const unsigned char* __restrict__ code4,
    unsigned int* __restrict__ gslotG, unsigned int* __restrict__ gtG,
    unsigned int* __restrict__ gtnG, float* __restrict__ x16G) {
  __shared__ unsigned int slots[256 * 9];  // [thread][group 0..7 | 8=dump]; key or 0
  __shared__ float4 cand4[CAPQ_];
  __shared__ int cnt;
  __shared__ float s_x16;
  __shared__ int s_flag, s_red;
  __shared__ unsigned int wb[4];

  const int g = (int)blockIdx.x >> 11;
  const int r = (int)blockIdx.x & 2047;
  const int t = threadIdx.x;
  const int lead = (4 - ((r * C_) & 3)) & 3;   // C%4==1 -> per-row misalignment
  const int n4 = (C_ - lead) >> 2;             // 2400 or 2401
  const size_t rowb = (size_t)r * C_;

  if (g == 0) {
    // ============================ x pass ============================
#pragma unroll
    for (int i = 0; i < 9; ++i) slots[t * 9 + i] = 0u;  // 0 = empty sentinel
    if (t == 0) { cnt = 0; s_flag = 0; }
    __syncthreads();

    const float* xb = x + rowb + lead;
    const unsigned int* cb = (const unsigned int*)(code4 + (size_t)lead * CS_);

#pragma unroll
    for (int k = 0; k < 10; ++k) {
      const int j = t + (k << 8);
      if (j < n4) {
        float4 X = *reinterpret_cast<const float4*>(xb + (j << 2));
        unsigned int cw = cb[j];  // codes of classes lead+4j .. lead+4j+3
        // Branchless per-element group-max: key=0 unless x>0; slot 8 = dump
        // for non-whitelist codes. Private address -> ds_max, no contention.
        {
          unsigned int k0 = (X.x > 0.0f) ? (__float_as_uint(X.x) | 0x80000000u) : 0u;
          unsigned int k1 = (X.y > 0.0f) ? (__float_as_uint(X.y) | 0x80000000u) : 0u;
          unsigned int k2 = (X.z > 0.0f) ? (__float_as_uint(X.z) | 0x80000000u) : 0u;
          unsigned int k3 = (X.w > 0.0f) ? (__float_as_uint(X.w) | 0x80000000u) : 0u;
          unsigned int a0 = min(cw & 0xFFu, 8u);
          unsigned int a1 = min((cw >> 8) & 0xFFu, 8u);
          unsigned int a2 = min((cw >> 16) & 0xFFu, 8u);
          unsigned int a3 = min(cw >> 24, 8u);
          atomicMax(&slots[t * 9 + a0], k0);
          atomicMax(&slots[t * 9 + a1], k1);
          atomicMax(&slots[t * 9 + a2], k2);
          atomicMax(&slots[t * 9 + a3], k3);
        }
        // Quad-granular candidate capture (junk <= T0 harmless; all > T0
        // captured => 16th-largest exact whenever it is > T0).
        float mx = fmaxf(fmaxf(X.x, X.y), fmaxf(X.z, X.w));
        if (mx > T0_) {
          int p = atomicAdd(&cnt, 1);
          if (p < CAPQ_) cand4[p] = X;
        }
      }
    }

    // Scalar head (c < lead) and tail, <= 3 elements each; own slots.
    if (t < 4) {
      auto sc = [&](int c) {
        float xv = x[rowb + c];
        unsigned int cd = code4[c];  // copy 0 = plain codes
        unsigned int key = (xv > 0.0f) ? (__float_as_uint(xv) | 0x80000000u) : 0u;
        atomicMax(&slots[t * 9 + min(cd, 8u)], key);
        if (xv > T0_) {
          int p = atomicAdd(&cnt, 1);
          if (p < CAPQ_) cand4[p] = make_float4(xv, -INFINITY, -INFINITY, -INFINITY);
        }
      };
      if (t < lead) sc(t);
      int c2 = lead + (n4 << 2) + t;
      if (c2 < C_) sc(c2);
    }
    __syncthreads();

    // Tree-reduce per-thread slots down to slots[0..7].
    for (int s = 128; s > 0; s >>= 1) {
      if (t < s) {
#pragma unroll
        for (int l = 0; l < 8; ++l) {
          unsigned int o = slots[(t + s) * 9 + l];
          if (o > slots[t * 9 + l]) slots[t * 9 + l] = o;
        }
      }
      __syncthreads();
    }
    if (t < 8) gslotG[r * 8 + t] = slots[t];  // exclusive owner: plain store

    // Exact 16th-largest (wave 0, registers, bisection on ordered keys).
    const int qn = cnt;
    const bool ok_path = (qn >= 4) && (qn <= CAPQ_);
    if (ok_path && t < 64) {
      const float* cf = reinterpret_cast<const float*>(cand4);
      const int nvv = qn << 2;
      unsigned int ku[CAPQ_ * 4 / 64];  // 24 keys/lane, statically indexed
#pragma unroll
      for (int k = 0; k < CAPQ_ * 4 / 64; ++k) {
        int i = t + (k << 6);
        ku[k] = (i < nvv) ? fkey(cf[i]) : 0u;
      }
      unsigned int lo = 0u, hi = 0xFFFFFFFFu;
#pragma unroll 1
      for (int it = 0; it < 32 && lo < hi; ++it) {
        unsigned int mid = lo + ((hi - lo) >> 1) + 1u;
        int c16 = 0;
#pragma unroll
        for (int k = 0; k < CAPQ_ * 4 / 64; ++k) c16 += (ku[k] >= mid) ? 1 : 0;
#pragma unroll
        for (int off = 32; off > 0; off >>= 1) c16 += __shfl_xor(c16, off, 64);
        if (c16 >= TOPK_) lo = mid; else hi = mid - 1u;
      }
      if (t == 0) {
        float v = fkeyinv(lo);
        s_x16 = v;
        s_flag = (v > T0_) ? 1 : 0;
      }
    }
    __syncthreads();
    if (!(ok_path && s_flag != 0)) {
      // Fallback (statistically never): exact block-wide bisection over row.
      const float* xr = x + rowb;
      unsigned int lo = 0u, hi = 0xFFFFFFFFu;
      for (int it = 0; it < 32; ++it) {
        if (lo >= hi) break;
        unsigned int mid = lo + ((hi - lo) >> 1) + 1u;
        if (t == 0) s_red = 0;
        __syncthreads();
        int cl = 0;
        for (int c = t; c < C_; c += 256) cl += (fkey(xr[c]) >= mid) ? 1 : 0;
        atomicAdd(&s_red, cl);
        __syncthreads();
        int total = s_red;
        __syncthreads();
        if (total >= TOPK_) lo = mid; else hi = mid - 1u;
      }
      if (t == 0) s_x16 = fkeyinv(lo);
    }
    __syncthreads();
    if (t == 0) x16G[r] = s_x16;
  } else {
    // ============================ y / yn pass ============================
    const float* src = (g == 1) ? y : yn;
    unsigned int* dst = (g == 1) ? gtG : gtnG;
    const float* sb = src + rowb + lead;
    unsigned int bits = 0u;

#pragma unroll
    for (int k = 0; k < 10; ++k) {
      const int j = t + (k << 8);
      if (j < n4) {
        float4 V = *reinterpret_cast<const float4*>(sb + (j << 2));
        if (V.x > 0.0f || V.y > 0.0f || V.z > 0.0f || V.w > 0.0f) {  // ~0.6%
          int c = lead + (j << 2);
          if (V.x > 0.0f) { unsigned int cd = code4[c];     if (cd < 8u) bits |= 1u << cd; }
          if (V.y > 0.0f) { unsigned int cd = code4[c + 1]; if (cd < 8u) bits |= 1u << cd; }
          if (V.z > 0.0f) { unsigned int cd = code4[c + 2]; if (cd < 8u) bits |= 1u << cd; }
          if (V.w > 0.0f) { unsigned int cd = code4[c + 3]; if (cd < 8u) bits |= 1u << cd; }
        }
      }
    }
    if (t < 4) {  // head/tail scalars
      if (t < lead) {
        float v = src[rowb + t];
        if (v > 0.0f) { unsigned int cd = code4[t]; if (cd < 8u) bits |= 1u << cd; }
      }
      int c2 = lead + (n4 << 2) + t;
      if (c2 < C_) {
        float v = src[rowb + c2];
        if (v > 0.0f) { unsigned int cd = code4[c2]; if (cd < 8u) bits |= 1u << cd; }
      }
    }
#pragma unroll
    for (int off = 32; off > 0; off >>= 1) bits |= __shfl_xor(bits, off, 64);
    if ((t & 63) == 0) wb[t >> 6] = bits;
    __syncthreads();
    if (t == 0) dst[r] = wb[0] | wb[1] | wb[2] | wb[3];  // exclusive owner
  }
}

// Finish: per-row loss epilogue (one thread per row; tables are L2-hot).
__global__ void finish_kernel(const unsigned int* __restrict__ gslotG,
                              const unsigned int* __restrict__ gtG,
                              const unsigned int* __restrict__ gtnG,
                              const float* __restrict__ x16G,
                              float* __restrict__ loss) {
  const int r = blockIdx.x * 256 + threadIdx.x;
  if (r >= B_) return;
  float thres = fmaxf(sigm(x16G[r]), 0.3f);
  unsigned int gtb = gtG[r], gnb = gtnG[r];
  float caseB = 0.0f, unio = -INFINITY, negmax = -INFINITY;
#pragma unroll
  for (int l = 0; l < L_; ++l) {
    // Decode positive-float key (0 sentinel -> -0.0f -> sigm = 0.5, matching
    // the P(group max <= 0) = 2^-240 convention proven in rounds 0-6).
    float gm = __uint_as_float(gslotG[r * L_ + l] ^ 0x80000000u);
    float g = sigm(gm);
    unio = fmaxf(unio, g);
    caseB += ((gtb >> l) & 1u) ? rank_loss(g, thres) : rank_loss(thres, g);
    if ((gnb >> l) & 1u) negmax = fmaxf(negmax, g);
  }
  float negscore = (gnb != 0u) ? negmax : 0.0f;
  float caseA = 0.5f * rank_loss(thres, unio) + 0.5f * rank_loss(thres, negscore);
  loss[r] = (gtb != 0u) ? caseB : caseA;
}

// Deterministic mean of the 2048 per-row losses.
__global__ void mean_kernel(const float* __restrict__ loss, float* __restrict__ out) {
  const int t = threadIdx.x;
  float s = 0.0f;
  for (int i = t; i < B_; i += 256) s += loss[i];
#pragma unroll
  for (int off = 32; off > 0; off >>= 1) s += __shfl_xor(s, off, 64);
  __shared__ float part[4];
  if ((t & 63) == 0) part[t >> 6] = s;
  __syncthreads();
  if (t == 0) out[0] = (part[0] + part[1] + part[2] + part[3]) * (1.0f / (float)B_);
}

extern "C" void kernel_launch(void* const* d_in, const int* in_sizes, int n_in,
                              void* d_out, int out_size, void* d_ws, size_t ws_size,
                              hipStream_t stream) {
  const float* x = (const float*)d_in[0];
  const float* y = (const float*)d_in[1];
  const float* yn = (const float*)d_in[2];
  const int* mask = (const int*)d_in[3];  // bool promoted to int32 by harness

  // Workspace layout (~137 KB; ws_size proven >= 4.33 MB in rounds 4/6/7).
  constexpr size_t OFF_LOSS = 0;                       // 2048 f32
  constexpr size_t OFF_CODE4 = 8192;                   // 4*CS_ bytes
  constexpr size_t OFF_GSLOT = OFF_CODE4 + 4 * CS_;    // 2048*8 u32
  constexpr size_t OFF_GT = OFF_GSLOT + B_ * L_ * 4;   // 2048 u32
  constexpr size_t OFF_GTN = OFF_GT + B_ * 4;          // 2048 u32
  constexpr size_t OFF_X16 = OFF_GTN + B_ * 4;         // 2048 f32

  float* loss = (float*)((char*)d_ws + OFF_LOSS);
  unsigned char* code4 = (unsigned char*)d_ws + OFF_CODE4;
  unsigned int* gslotG = (unsigned int*)((char*)d_ws + OFF_GSLOT);
  unsigned int* gtG = (unsigned int*)((char*)d_ws + OFF_GT);
  unsigned int* gtnG = (unsigned int*)((char*)d_ws + OFF_GTN);
  float* x16G = (float*)((char*)d_ws + OFF_X16);

  hipLaunchKernelGGL(setup_kernel, dim3(38), dim3(256), 0, stream,
                     mask, code4, gtG, gtnG);
  hipLaunchKernelGGL(rows3_kernel, dim3(3 * B_), dim3(256), 0, stream,
                     x, y, yn, code4, gslotG, gtG, gtnG, x16G);
  hipLaunchKernelGGL(finish_kernel, dim3((B_ + 255) / 256), dim3(256), 0, stream,
                     gslotG, gtG, gtnG, x16G, loss);
  hipLaunchKernelGGL(mean_kernel, dim3(1), dim3(256), 0, stream,
                     loss, (float*)d_out);
}